// Round 1
// baseline (4111.667 us; speedup 1.0000x reference)
//
#include <hip/hip_runtime.h>
#include <math.h>

// Problem constants
#define DIMN 128
#define N_I 65536
#define N_C 8192
#define E_I 524288
#define E_C 65536
#define TT 102400
#define SS 2048
#define VV 100000

// ---------------------------------------------------------------------------
// Edge aggregation: agg[dst] += w * table[node2row[src]]   (fp32 atomics)
// One thread per (edge, 4-dim group): gid>>5 = edge, gid&31 = float4 index
// ---------------------------------------------------------------------------
__global__ void edge_agg_kernel(const int* __restrict__ e_src,
                                const int* __restrict__ e_dst,
                                const float* __restrict__ ew,
                                const int* __restrict__ node2row,
                                const float* __restrict__ table,
                                float* __restrict__ agg, int E) {
    int gid = blockIdx.x * blockDim.x + threadIdx.x;
    int e = gid >> 5;
    int q = gid & 31;
    if (e >= E) return;
    int src = e_src[e];
    int dst = e_dst[e];
    float w = ew[e];
    int row = node2row[src];
    const float4 v = *(const float4*)&table[(size_t)row * DIMN + q * 4];
    float* out = &agg[(size_t)dst * DIMN + q * 4];
    atomicAdd(out + 0, w * v.x);
    atomicAdd(out + 1, w * v.y);
    atomicAdd(out + 2, w * v.z);
    atomicAdd(out + 3, w * v.w);
}

// ---------------------------------------------------------------------------
// Generic fp32 GEMM:  C[M,N] = A[M,K] * B[N,K]^T (+ bias[n])
// 64x64 tile, KT=32, 256 threads, 4x4 accum per thread.
// ---------------------------------------------------------------------------
#define KT 32
__global__ __launch_bounds__(256) void gemm_abt(const float* __restrict__ A,
                                                const float* __restrict__ B,
                                                const float* __restrict__ bias,
                                                float* __restrict__ C,
                                                int M, int N, int K) {
    __shared__ float a_t[KT][68];  // [k][m], pad 68 -> 16B-aligned float4 rows
    __shared__ float b_t[KT][68];  // [k][n]
    int tid = threadIdx.x;
    int bm = blockIdx.y * 64;
    int bn = blockIdx.x * 64;
    int tx = tid & 15;
    int ty = tid >> 4;
    float acc[4][4] = {};
    for (int k0 = 0; k0 < K; k0 += KT) {
        for (int i = tid; i < 64 * KT; i += 256) {
            int m = i >> 5;
            int k = i & 31;
            int gm = bm + m;
            int gn = bn + m;
            a_t[k][m] = (gm < M) ? A[(size_t)gm * K + k0 + k] : 0.f;
            b_t[k][m] = (gn < N) ? B[(size_t)gn * K + k0 + k] : 0.f;
        }
        __syncthreads();
#pragma unroll
        for (int k = 0; k < KT; ++k) {
            float4 af = *(const float4*)&a_t[k][ty * 4];
            float4 bf = *(const float4*)&b_t[k][tx * 4];
            float am[4] = {af.x, af.y, af.z, af.w};
            float bv[4] = {bf.x, bf.y, bf.z, bf.w};
#pragma unroll
            for (int i = 0; i < 4; ++i)
#pragma unroll
                for (int j = 0; j < 4; ++j)
                    acc[i][j] += am[i] * bv[j];
        }
        __syncthreads();
    }
#pragma unroll
    for (int i = 0; i < 4; ++i) {
        int gm = bm + ty * 4 + i;
        if (gm >= M) continue;
#pragma unroll
        for (int j = 0; j < 4; ++j) {
            int gn = bn + tx * 4 + j;
            if (gn >= N) continue;
            float v = acc[i][j] + (bias ? bias[gn] : 0.f);
            C[(size_t)gm * N + gn] = v;
        }
    }
}

// ---------------------------------------------------------------------------
// eft[t, 0:128] = node_i[item2idx[t]] ; eft[t, 128:256] = node_c[cat2idx[t]]
// ---------------------------------------------------------------------------
__global__ void gather_eft_kernel(const float* __restrict__ node_i,
                                  const float* __restrict__ node_c,
                                  const int* __restrict__ i2x,
                                  const int* __restrict__ c2x,
                                  float* __restrict__ eft) {
    int gid = blockIdx.x * blockDim.x + threadIdx.x;
    int t = gid >> 6;
    int q = gid & 63;
    if (t >= TT) return;
    float4 v;
    if (q < 32)
        v = *(const float4*)&node_i[(size_t)i2x[t] * DIMN + q * 4];
    else
        v = *(const float4*)&node_c[(size_t)c2x[t] * DIMN + (q - 32) * 4];
    *(float4*)&eft[(size_t)t * 256 + q * 4] = v;
}

// ---------------------------------------------------------------------------
// Session boundaries from sorted segment_ids. segst preset to -1, segend to 0.
// ---------------------------------------------------------------------------
__global__ void bounds_kernel(const int* __restrict__ seg,
                              int* __restrict__ segst,
                              int* __restrict__ segend) {
    int t = blockIdx.x * blockDim.x + threadIdx.x;
    if (t >= TT) return;
    int s = seg[t];
    if (t == 0 || seg[t - 1] != s) segst[s] = t;
    if (t == TT - 1 || seg[t + 1] != s) segend[s] = t + 1;
}

// ---------------------------------------------------------------------------
// hv[s] = eft[last_idx[s]] @ w2^T   (no bias). last = max(segend-1, 0).
// One block (256 threads) per session.
// ---------------------------------------------------------------------------
__global__ __launch_bounds__(256) void hv_kernel(const float* __restrict__ eft,
                                                 const int* __restrict__ segend,
                                                 const float* __restrict__ w2,
                                                 float* __restrict__ hv) {
    int s = blockIdx.x;
    int d = threadIdx.x;
    __shared__ float x[256];
    int li = segend[s] - 1;
    if (li < 0) li = 0;
    x[d] = eft[(size_t)li * 256 + d];
    __syncthreads();
    float acc = 0.f;
    const float* wr = &w2[(size_t)d * 256];
    for (int k = 0; k < 256; k += 4) {
        float4 wv = *(const float4*)&wr[k];
        acc += x[k] * wv.x + x[k + 1] * wv.y + x[k + 2] * wv.z + x[k + 3] * wv.w;
    }
    hv[(size_t)s * 256 + d] = acc;
}

// ---------------------------------------------------------------------------
// alpha[t] = q_W . sigmoid(U[t] + w1_b + hv[seg[t]]) + q_b
// One block (256 threads) per position.
// ---------------------------------------------------------------------------
__global__ __launch_bounds__(256) void alpha_kernel(const float* __restrict__ U,
                                                    const float* __restrict__ w1b,
                                                    const float* __restrict__ hv,
                                                    const int* __restrict__ seg,
                                                    const float* __restrict__ qW,
                                                    const float* __restrict__ qb,
                                                    float* __restrict__ alpha) {
    int t = blockIdx.x;
    int d = threadIdx.x;
    int s = seg[t];
    float v = U[(size_t)t * 256 + d] + w1b[d] + hv[(size_t)s * 256 + d];
    float sgm = 1.f / (1.f + expf(-v));
    float p = sgm * qW[d];
#pragma unroll
    for (int off = 32; off > 0; off >>= 1) p += __shfl_down(p, off, 64);
    __shared__ float red[4];
    if ((d & 63) == 0) red[d >> 6] = p;
    __syncthreads();
    if (d == 0) alpha[t] = red[0] + red[1] + red[2] + red[3] + qb[0];
}

// ---------------------------------------------------------------------------
// sg[s] = sum over session positions of alpha[t] * eft[t].  Sessions are
// contiguous (sorted segment_ids): one block per session, thread=dim.
// ---------------------------------------------------------------------------
__global__ __launch_bounds__(256) void sg_kernel(const float* __restrict__ eft,
                                                 const float* __restrict__ alpha,
                                                 const int* __restrict__ segst,
                                                 const int* __restrict__ segend,
                                                 float* __restrict__ sgout) {
    int s = blockIdx.x;
    int d = threadIdx.x;
    float acc = 0.f;
    int st = segst[s];
    int en = segend[s];
    if (st >= 0) {
        for (int t = st; t < en; ++t)
            acc += alpha[t] * eft[(size_t)t * 256 + d];
    }
    sgout[(size_t)s * 256 + d] = acc;
}

// ---------------------------------------------------------------------------
// all_item[v] = concat(item_emb_table[v], cat_emb_table[cat4item[v]])
// ---------------------------------------------------------------------------
__global__ void gather_allitem_kernel(const float* __restrict__ itab,
                                      const float* __restrict__ ctab,
                                      const int* __restrict__ c4i,
                                      float* __restrict__ allit) {
    int gid = blockIdx.x * blockDim.x + threadIdx.x;
    int v = gid >> 6;
    int q = gid & 63;
    if (v >= VV) return;
    float4 val;
    if (q < 32)
        val = *(const float4*)&itab[(size_t)v * DIMN + q * 4];
    else
        val = *(const float4*)&ctab[(size_t)c4i[v] * DIMN + (q - 32) * 4];
    *(float4*)&allit[(size_t)v * 256 + q * 4] = val;
}

// ---------------------------------------------------------------------------
// Launch
// ---------------------------------------------------------------------------
extern "C" void kernel_launch(void* const* d_in, const int* in_sizes, int n_in,
                              void* d_out, int out_size, void* d_ws, size_t ws_size,
                              hipStream_t stream) {
    const int* items      = (const int*)d_in[0];
    const int* cats       = (const int*)d_in[1];
    const int* item2idx   = (const int*)d_in[2];
    const int* cat2idx    = (const int*)d_in[3];
    const int* item_e     = (const int*)d_in[4];   // [2, E_I]
    const int* cat_e      = (const int*)d_in[5];   // [2, E_C]
    const float* item_e_w = (const float*)d_in[6];
    const float* cat_e_w  = (const float*)d_in[7];
    const int* segment_ids= (const int*)d_in[8];
    const int* cat4item   = (const int*)d_in[9];
    const float* item_tab = (const float*)d_in[10]; // [100000,128]
    const float* cat_tab  = (const float*)d_in[11]; // [1000,128]
    const float* i_gnn_W  = (const float*)d_in[12];
    const float* i_gnn_b  = (const float*)d_in[13];
    const float* c_gnn_W  = (const float*)d_in[14];
    const float* c_gnn_b  = (const float*)d_in[15];
    const float* w1_W     = (const float*)d_in[16];
    const float* w1_b     = (const float*)d_in[17];
    const float* w2_W     = (const float*)d_in[18];
    const float* q_W      = (const float*)d_in[19];
    const float* q_b      = (const float*)d_in[20];
    float* out = (float*)d_out;

    // Workspace layout (floats). agg buffers alias the eft region (dead before
    // eft is written); all_item aliases U (U dead after alpha_kernel).
    float* wsf = (float*)d_ws;
    const size_t F_NODE_I = (size_t)N_I * DIMN;       // 8388608
    const size_t F_NODE_C = (size_t)N_C * DIMN;       // 1048576
    const size_t F_EFT    = (size_t)TT * 256;         // 26214400
    const size_t F_U      = (size_t)TT * 256;         // >= VV*256
    const size_t F_HV     = (size_t)SS * 256;
    const size_t F_ALPHA  = (size_t)TT;
    const size_t F_SG     = (size_t)SS * 256;

    float* node_i = wsf;
    float* node_c = node_i + F_NODE_I;
    float* eft    = node_c + F_NODE_C;
    float* agg_i  = eft;                 // alias
    float* agg_c  = eft + F_NODE_I;      // alias (fits inside eft region)
    float* U      = eft + F_EFT;
    float* allit  = U;                   // alias
    float* hv     = U + F_U;
    float* alphaA = hv + F_HV;
    float* sgbuf  = alphaA + F_ALPHA;
    int* segst    = (int*)(sgbuf + F_SG);
    int* segend   = segst + SS;

    // 1. zero / init scratch
    hipMemsetAsync(agg_i, 0, F_NODE_I * sizeof(float), stream);
    hipMemsetAsync(agg_c, 0, F_NODE_C * sizeof(float), stream);
    hipMemsetAsync(segst, 0xFF, SS * sizeof(int), stream);   // -1
    hipMemsetAsync(segend, 0, SS * sizeof(int), stream);

    // 2. edge aggregation (atomics)
    {
        int n = E_I * 32;
        edge_agg_kernel<<<(n + 255) / 256, 256, 0, stream>>>(
            item_e, item_e + E_I, item_e_w, items, item_tab, agg_i, E_I);
        n = E_C * 32;
        edge_agg_kernel<<<(n + 255) / 256, 256, 0, stream>>>(
            cat_e, cat_e + E_C, cat_e_w, cats, cat_tab, agg_c, E_C);
    }

    // 3. node linears: node = agg @ W^T + b
    {
        dim3 g((DIMN + 63) / 64, (N_I + 63) / 64);
        gemm_abt<<<g, 256, 0, stream>>>(agg_i, i_gnn_W, i_gnn_b, node_i,
                                        N_I, DIMN, DIMN);
        dim3 g2((DIMN + 63) / 64, (N_C + 63) / 64);
        gemm_abt<<<g2, 256, 0, stream>>>(agg_c, c_gnn_W, c_gnn_b, node_c,
                                         N_C, DIMN, DIMN);
    }

    // 4. eft gather (overwrites agg alias region — safe, stream-ordered)
    {
        int n = TT * 64;
        gather_eft_kernel<<<(n + 255) / 256, 256, 0, stream>>>(
            node_i, node_c, item2idx, cat2idx, eft);
    }

    // 5. session bounds
    bounds_kernel<<<(TT + 255) / 256, 256, 0, stream>>>(segment_ids, segst, segend);

    // 6. hv per session
    hv_kernel<<<SS, 256, 0, stream>>>(eft, segend, w2_W, hv);

    // 7. U = eft @ w1^T + w1_b
    {
        dim3 g((256 + 63) / 64, (TT + 63) / 64);
        gemm_abt<<<g, 256, 0, stream>>>(eft, w1_W, w1_b, U, TT, 256, 256);
    }

    // 8. alpha
    alpha_kernel<<<TT, 256, 0, stream>>>(U, w1_b, hv, segment_ids, q_W, q_b, alphaA);

    // 9. sg per session
    sg_kernel<<<SS, 256, 0, stream>>>(eft, alphaA, segst, segend, sgbuf);

    // 10. all_item gather (overwrites U alias — after alpha, safe)
    {
        int n = VV * 64;
        gather_allitem_kernel<<<(n + 255) / 256, 256, 0, stream>>>(
            item_tab, cat_tab, cat4item, allit);
    }

    // 11. out = sg @ all_item^T
    {
        dim3 g((VV + 63) / 64, (SS + 63) / 64);
        gemm_abt<<<g, 256, 0, stream>>>(sgbuf, allit, nullptr, out, SS, VV, 256);
    }
}